// Round 1
// baseline (706.882 us; speedup 1.0000x reference)
//
#include <hip/hip_runtime.h>
#include <stdint.h>

#define WW 1024
#define HH 1024
#define NB 4
#define NPIX (NB * HH * WW)   // 4194304
#define INVALID 0xFFFFFFFFu

// counters (uint32 words):
// scratch: [0]=min_bits [1]=max_bits [2]=numFg [3]=roots(>0) [4]=root0_flag
// persist: [8]=ccs_uniq [9]=ccsg_uniq [10]=numSg_float_bits

__global__ void k_zero(uint32_t* c, int first) {
    c[0] = 0x7F800000u;  // +inf (all data values are >= 0, so uint-bit order == float order)
    c[1] = 0u;           // max seed 0.0f
    c[2] = 0u; c[3] = 0u; c[4] = 0u;
    if (first) { c[8] = 0u; c[9] = 0u; c[10] = 0u; }
}

// erosion with cross SE (pad=BIG => just skip out-of-bounds)
__global__ void k_erode(const float* __restrict__ in, float* __restrict__ out) {
    int i = blockIdx.x * 256 + threadIdx.x;
    int x = i & (WW - 1);
    int y = (i >> 10) & (HH - 1);
    float v = in[i];
    if (x > 0)      v = fminf(v, in[i - 1]);
    if (x < WW - 1) v = fminf(v, in[i + 1]);
    if (y > 0)      v = fminf(v, in[i - WW]);
    if (y < HH - 1) v = fminf(v, in[i + WW]);
    out[i] = v;
}

// dilation with cross SE (pad=-BIG => skip out-of-bounds)
__global__ void k_dilate(const float* __restrict__ in, float* __restrict__ out) {
    int i = blockIdx.x * 256 + threadIdx.x;
    int x = i & (WW - 1);
    int y = (i >> 10) & (HH - 1);
    float v = in[i];
    if (x > 0)      v = fmaxf(v, in[i - 1]);
    if (x < WW - 1) v = fmaxf(v, in[i + 1]);
    if (y > 0)      v = fmaxf(v, in[i - WW]);
    if (y < HH - 1) v = fmaxf(v, in[i + WW]);
    out[i] = v;
}

__global__ void k_minmax(const float* __restrict__ in, uint32_t* c) {
    float lmin = __uint_as_float(0x7F800000u);  // +inf
    float lmax = 0.0f;                          // data >= 0
    int stride = gridDim.x * blockDim.x;
    for (int i = blockIdx.x * blockDim.x + threadIdx.x; i < NPIX; i += stride) {
        float v = in[i];
        lmin = fminf(lmin, v);
        lmax = fmaxf(lmax, v);
    }
    for (int off = 32; off > 0; off >>= 1) {
        lmin = fminf(lmin, __shfl_down(lmin, off));
        lmax = fmaxf(lmax, __shfl_down(lmax, off));
    }
    __shared__ float smin[4], smax[4];
    int wave = threadIdx.x >> 6;
    if ((threadIdx.x & 63) == 0) { smin[wave] = lmin; smax[wave] = lmax; }
    __syncthreads();
    if (threadIdx.x == 0) {
        float m0 = fminf(fminf(smin[0], smin[1]), fminf(smin[2], smin[3]));
        float m1 = fmaxf(fmaxf(smax[0], smax[1]), fmaxf(smax[2], smax[3]));
        // non-negative floats: uint bit pattern is order-isomorphic
        atomicMin(&c[0], __float_as_uint(m0));
        atomicMax(&c[1], __float_as_uint(m1));
    }
}

// binarize + union-find init fused: P[i] = i if fg else INVALID; count fg.
__global__ void k_binarize(const float* __restrict__ opened, uint32_t* c,
                           uint32_t* __restrict__ P) {
    float mn = __uint_as_float(c[0]);
    float mx = __uint_as_float(c[1]);
    float denom = (mx - mn) + 1e-10f;  // same assoc order as reference
    uint32_t cnt = 0;
    int stride = gridDim.x * blockDim.x;
    for (int i = blockIdx.x * blockDim.x + threadIdx.x; i < NPIX; i += stride) {
        float nv = (opened[i] - mn) / denom;   // IEEE f32 div, matches jnp
        bool m = (nv >= 0.5f);
        P[i] = m ? (uint32_t)i : INVALID;
        cnt += m ? 1u : 0u;
    }
    for (int off = 32; off > 0; off >>= 1) cnt += __shfl_down(cnt, off);
    __shared__ uint32_t s[4];
    if ((threadIdx.x & 63) == 0) s[threadIdx.x >> 6] = cnt;
    __syncthreads();
    if (threadIdx.x == 0) {
        uint32_t t = s[0] + s[1] + s[2] + s[3];
        if (t) atomicAdd(&c[2], t);
    }
}

__device__ __forceinline__ uint32_t pload(uint32_t* P, uint32_t x) {
    return __hip_atomic_load(&P[x], __ATOMIC_RELAXED, __HIP_MEMORY_SCOPE_AGENT);
}

__device__ __forceinline__ uint32_t uf_find(uint32_t* P, uint32_t x) {
    uint32_t p = pload(P, x);
    while (p != x) {
        uint32_t gp = pload(P, p);
        if (gp != p)
            __hip_atomic_store(&P[x], gp, __ATOMIC_RELAXED, __HIP_MEMORY_SCOPE_AGENT);
        x = p;
        p = gp;
    }
    return x;
}

// max-convention union: always link lower root under higher root,
// so the surviving root of each component is its maximum pixel index
// (== the converged label of the reference's max-pool propagation).
__device__ void uf_union(uint32_t* P, uint32_t a, uint32_t b) {
    uint32_t ra = uf_find(P, a);
    uint32_t rb = uf_find(P, b);
    while (ra != rb) {
        uint32_t hi = ra > rb ? ra : rb;
        uint32_t lo = ra > rb ? rb : ra;
        uint32_t old = atomicCAS(&P[lo], lo, hi);
        if (old == lo) return;
        ra = uf_find(P, old);
        rb = uf_find(P, hi);
    }
}

// each fg pixel unions with its W, NW, N, NE fg neighbors (covers all
// 8-connectivity edges exactly once). fg test: P[n] != INVALID (fg values
// never become INVALID, bg values never leave INVALID).
__global__ void k_union(uint32_t* P) {
    int i = blockIdx.x * 256 + threadIdx.x;
    if (P[i] == INVALID) return;
    int x = i & (WW - 1);
    int y = (i >> 10) & (HH - 1);
    if (x > 0 && P[i - 1] != INVALID) uf_union(P, (uint32_t)i, (uint32_t)(i - 1));
    if (y > 0) {
        if (P[i - WW] != INVALID)               uf_union(P, (uint32_t)i, (uint32_t)(i - WW));
        if (x > 0 && P[i - WW - 1] != INVALID)  uf_union(P, (uint32_t)i, (uint32_t)(i - WW - 1));
        if (x < WW - 1 && P[i - WW + 1] != INVALID) uf_union(P, (uint32_t)i, (uint32_t)(i - WW + 1));
    }
}

__global__ void k_count(const uint32_t* __restrict__ P, uint32_t* c) {
    uint32_t roots = 0;
    int stride = gridDim.x * blockDim.x;
    for (int i = blockIdx.x * blockDim.x + threadIdx.x; i < NPIX; i += stride) {
        uint32_t p = P[i];
        if (p == (uint32_t)i && p != INVALID) {
            if (i > 0) roots++;
            else atomicOr(&c[4], 1u);  // singleton component at pixel 0 -> label value 0
        }
    }
    for (int off = 32; off > 0; off >>= 1) roots += __shfl_down(roots, off);
    __shared__ uint32_t s[4];
    if ((threadIdx.x & 63) == 0) s[threadIdx.x >> 6] = roots;
    __syncthreads();
    if (threadIdx.x == 0) {
        uint32_t t = s[0] + s[1] + s[2] + s[3];
        if (t) atomicAdd(&c[3], t);
    }
}

__global__ void k_fin_input(uint32_t* c, int is_lab) {
    uint32_t numFg = c[2];
    // a zero value exists iff there is any background pixel, or pixel 0 is a
    // singleton fg component (its converged label is 0).
    uint32_t uniq = c[3] + ((numFg < (uint32_t)NPIX || c[4]) ? 1u : 0u);
    if (is_lab) {
        c[9] = uniq;
        c[10] = __float_as_uint((float)numFg);  // numSg: exact integer < 2^24
    } else {
        c[8] = uniq;
    }
}

__global__ void k_final(const uint32_t* __restrict__ c, float* __restrict__ out) {
    float ccs = (float)c[8];
    float ccsg = (float)c[9];
    float numSg = __uint_as_float(c[10]);
    out[0] = fabsf(ccsg - ccs) / numSg;
}

extern "C" void kernel_launch(void* const* d_in, const int* in_sizes, int n_in,
                              void* d_out, int out_size, void* d_ws, size_t ws_size,
                              hipStream_t stream) {
    const float* img = (const float*)d_in[0];
    const float* lab = (const float*)d_in[1];
    float* out = (float*)d_out;
    char* ws = (char*)d_ws;

    float* bufA = (float*)ws;                                      // 16 MB (erosion out; later reused as parent)
    float* bufB = (float*)(ws + (size_t)NPIX * sizeof(float));     // 16 MB (opened)
    uint32_t* cnt = (uint32_t*)(ws + (size_t)2 * NPIX * sizeof(float));  // 64 B
    uint32_t* P = (uint32_t*)bufA;

    const int gridPix = NPIX / 256;  // 16384
    const int gridRed = 1024;

    for (int t = 0; t < 2; ++t) {
        const float* src = (t == 0) ? img : lab;
        k_zero<<<1, 1, 0, stream>>>(cnt, t == 0 ? 1 : 0);
        k_erode<<<gridPix, 256, 0, stream>>>(src, bufA);
        k_dilate<<<gridPix, 256, 0, stream>>>(bufA, bufB);
        k_minmax<<<gridRed, 256, 0, stream>>>(bufB, cnt);
        k_binarize<<<gridRed, 256, 0, stream>>>(bufB, cnt, P);  // P aliases bufA (dead after dilate)
        k_union<<<gridPix, 256, 0, stream>>>(P);
        k_count<<<gridRed, 256, 0, stream>>>(P, cnt);
        k_fin_input<<<1, 1, 0, stream>>>(cnt, t);
    }
    k_final<<<1, 1, 0, stream>>>(cnt, out);
}

// Round 2
// 559.050 us; speedup vs baseline: 1.2644x; 1.2644x over previous
//
#include <hip/hip_runtime.h>
#include <stdint.h>

#define WW 1024
#define HH 1024
#define NB 4
#define NPIX (NB * HH * WW)   // 4194304
#define NTILES (NB * 32 * 32) // 4096 tiles of 32x32
#define INVALID 0xFFFFFFFFu

// counters (uint32 words):
// scratch: [0]=min_bits [1]=max_bits [2]=numFg [3]=roots(>0) [4]=root0_flag
// persist: [8]=ccs_uniq [9]=ccsg_uniq [10]=numSg_float_bits

__global__ void k_zero(uint32_t* c, int first) {
    c[0] = 0x7F800000u;  // +inf (data >= 0 so uint-bit order == float order)
    c[1] = 0u;           // max seed 0.0f
    c[2] = 0u; c[3] = 0u; c[4] = 0u;
    if (first) { c[8] = 0u; c[9] = 0u; c[10] = 0u; }
}

// ---------------- fused opening (erode+dilate, cross SE) + global min/max ---
// One 32x32 tile per block. LDS halo: input needs +/-2, erosion needs +/-1.
__global__ void k_open(const float* __restrict__ in, float* __restrict__ out,
                       uint32_t* c) {
    int tile = blockIdx.x;
    int b  = tile >> 10;
    int t  = tile & 1023;
    int ty0 = (t >> 5) << 5;
    int tx0 = (t & 31) << 5;
    const float* img = in + (size_t)b * (HH * WW);
    float* outb      = out + (size_t)b * (HH * WW);

    __shared__ float s_in[36 * 36];
    __shared__ float s_er[34 * 34];

    for (int li = threadIdx.x; li < 36 * 36; li += 256) {
        int r = li / 36, cc = li - r * 36;
        int gy = ty0 - 2 + r, gx = tx0 - 2 + cc;
        float v = 1e10f;  // erosion pad = BIG
        if (gy >= 0 && gy < HH && gx >= 0 && gx < WW) v = img[gy * WW + gx];
        s_in[li] = v;
    }
    __syncthreads();

    for (int li = threadIdx.x; li < 34 * 34; li += 256) {
        int r = li / 34, cc = li - r * 34;     // er (r,cc) <-> image (ty0-1+r, tx0-1+cc)
        int gy = ty0 - 1 + r, gx = tx0 - 1 + cc;
        float e = -1e10f;  // dilation pad = -BIG for out-of-image erosion sites
        if (gy >= 0 && gy < HH && gx >= 0 && gx < WW) {
            int ii = (r + 1) * 36 + (cc + 1);
            float v = s_in[ii];
            v = fminf(v, s_in[ii - 1]);
            v = fminf(v, s_in[ii + 1]);
            v = fminf(v, s_in[ii - 36]);
            v = fminf(v, s_in[ii + 36]);
            e = v;
        }
        s_er[li] = e;
    }
    __syncthreads();

    float lmin = __uint_as_float(0x7F800000u);
    float lmax = 0.0f;
    for (int q = 0; q < 4; q++) {
        int li = q * 256 + threadIdx.x;
        int ly = li >> 5, lx = li & 31;
        int ei = (ly + 1) * 34 + (lx + 1);
        float v = s_er[ei];
        v = fmaxf(v, s_er[ei - 1]);
        v = fmaxf(v, s_er[ei + 1]);
        v = fmaxf(v, s_er[ei - 34]);
        v = fmaxf(v, s_er[ei + 34]);
        outb[(ty0 + ly) * WW + tx0 + lx] = v;
        lmin = fminf(lmin, v);
        lmax = fmaxf(lmax, v);
    }
    for (int off = 32; off > 0; off >>= 1) {
        lmin = fminf(lmin, __shfl_down(lmin, off));
        lmax = fmaxf(lmax, __shfl_down(lmax, off));
    }
    __shared__ float smin[4], smax[4];
    if ((threadIdx.x & 63) == 0) {
        smin[threadIdx.x >> 6] = lmin;
        smax[threadIdx.x >> 6] = lmax;
    }
    __syncthreads();
    if (threadIdx.x == 0) {
        float m0 = fminf(fminf(smin[0], smin[1]), fminf(smin[2], smin[3]));
        float m1 = fmaxf(fmaxf(smax[0], smax[1]), fmaxf(smax[2], smax[3]));
        atomicMin(&c[0], __float_as_uint(m0));  // non-negative floats
        atomicMax(&c[1], __float_as_uint(m1));
    }
}

// ---------------- LDS union-find helpers (workgroup scope) ------------------
__device__ __forceinline__ uint32_t lload(uint32_t* lp, uint32_t x) {
    return __hip_atomic_load(&lp[x], __ATOMIC_RELAXED, __HIP_MEMORY_SCOPE_WORKGROUP);
}
__device__ __forceinline__ uint32_t lfind(uint32_t* lp, uint32_t x) {
    uint32_t p = lload(lp, x);
    while (p != x) {
        uint32_t gp = lload(lp, p);
        if (gp != p)
            __hip_atomic_store(&lp[x], gp, __ATOMIC_RELAXED, __HIP_MEMORY_SCOPE_WORKGROUP);
        x = p; p = gp;
    }
    return x;
}
__device__ void lunion(uint32_t* lp, uint32_t a, uint32_t b) {
    uint32_t ra = lfind(lp, a), rb = lfind(lp, b);
    while (ra != rb) {
        uint32_t hi = ra > rb ? ra : rb;
        uint32_t lo = ra ^ rb ^ hi;
        uint32_t old = atomicCAS(&lp[lo], lo, hi);
        if (old == lo) return;
        ra = lfind(lp, old);
        rb = lfind(lp, hi);
    }
}

// ---------------- binarize + tile-local CCL ---------------------------------
// P[i] = global index of tile-local component max (or i itself), INVALID if bg.
__global__ void k_ccl(const float* __restrict__ opened, const uint32_t* __restrict__ c,
                      uint32_t* __restrict__ P) {
    int tile = blockIdx.x;
    int b  = tile >> 10;
    int t  = tile & 1023;
    int ty0 = (t >> 5) << 5;
    int tx0 = (t & 31) << 5;
    uint32_t base = (uint32_t)b * (HH * WW) + (uint32_t)ty0 * WW + tx0;

    float mn = __uint_as_float(c[0]);
    float mx = __uint_as_float(c[1]);
    float denom = (mx - mn) + 1e-10f;  // reference association order

    __shared__ uint32_t lp[1024];
    uint32_t fgcnt = 0;
    for (int q = 0; q < 4; q++) {
        int li = q * 256 + threadIdx.x;
        int ly = li >> 5, lx = li & 31;
        float nv = (opened[base + (uint32_t)ly * WW + lx] - mn) / denom;  // IEEE div
        bool m = (nv >= 0.5f);
        lp[li] = m ? (uint32_t)li : INVALID;
        fgcnt += m ? 1u : 0u;
    }
    __syncthreads();

    // local unions: W, N, NW, NE (covers all intra-tile 8-conn edges once)
    for (int q = 0; q < 4; q++) {
        int li = q * 256 + threadIdx.x;
        if (lload(lp, li) == INVALID) continue;
        int ly = li >> 5, lx = li & 31;
        if (lx > 0 && lload(lp, li - 1) != INVALID) lunion(lp, li, li - 1);
        if (ly > 0) {
            if (lload(lp, li - 32) != INVALID)              lunion(lp, li, li - 32);
            if (lx > 0 && lload(lp, li - 33) != INVALID)    lunion(lp, li, li - 33);
            if (lx < 31 && lload(lp, li - 31) != INVALID)   lunion(lp, li, li - 31);
        }
    }
    __syncthreads();

    // flatten + write global parents (depth-1 trees to tile-local max)
    for (int q = 0; q < 4; q++) {
        int li = q * 256 + threadIdx.x;
        int ly = li >> 5, lx = li & 31;
        uint32_t g;
        if (lp[li] == INVALID) g = INVALID;
        else {
            uint32_t r = lfind(lp, li);
            g = base + (uint32_t)(r >> 5) * WW + (r & 31);
        }
        P[base + (uint32_t)ly * WW + lx] = g;
    }

    for (int off = 32; off > 0; off >>= 1) fgcnt += __shfl_down(fgcnt, off);
    __shared__ uint32_t s[4];
    if ((threadIdx.x & 63) == 0) s[threadIdx.x >> 6] = fgcnt;
    __syncthreads();
    if (threadIdx.x == 0) {
        uint32_t tt = s[0] + s[1] + s[2] + s[3];
        if (tt) atomicAdd((uint32_t*)&c[2], tt);
    }
}

// ---------------- global union-find (device scope, cross-XCD safe) ----------
__device__ __forceinline__ uint32_t pload(uint32_t* P, uint32_t x) {
    return __hip_atomic_load(&P[x], __ATOMIC_RELAXED, __HIP_MEMORY_SCOPE_AGENT);
}
__device__ __forceinline__ uint32_t uf_find(uint32_t* P, uint32_t x) {
    uint32_t p = pload(P, x);
    while (p != x) {
        uint32_t gp = pload(P, p);
        if (gp != p)
            __hip_atomic_store(&P[x], gp, __ATOMIC_RELAXED, __HIP_MEMORY_SCOPE_AGENT);
        x = p; p = gp;
    }
    return x;
}
__device__ void uf_union(uint32_t* P, uint32_t a, uint32_t b) {
    uint32_t ra = uf_find(P, a);
    uint32_t rb = uf_find(P, b);
    while (ra != rb) {
        uint32_t hi = ra > rb ? ra : rb;
        uint32_t lo = ra ^ rb ^ hi;
        uint32_t old = atomicCAS(&P[lo], lo, hi);
        if (old == lo) return;
        ra = uf_find(P, old);
        rb = uf_find(P, hi);
    }
}

// border edges only: forward neighbors {E, S, SW, SE} that cross a tile edge
__global__ void k_border(uint32_t* P) {
    int i = blockIdx.x * 256 + threadIdx.x;
    int x = i & (WW - 1);
    int y = (i >> 10) & (HH - 1);
    int lx = x & 31, ly = y & 31;
    if (lx != 0 && lx != 31 && ly != 31) return;  // owns no cross-tile fwd edge
    if (P[i] == INVALID) return;
    bool xe = (x < WW - 1), ys = (y < HH - 1);
    if (lx == 31 && xe && P[i + 1] != INVALID) uf_union(P, i, i + 1);
    if (ys) {
        bool cS = (ly == 31);
        if (cS && P[i + WW] != INVALID)                         uf_union(P, i, i + WW);
        if ((cS || lx == 0)  && x > 0 && P[i + WW - 1] != INVALID) uf_union(P, i, i + WW - 1);
        if ((cS || lx == 31) && xe    && P[i + WW + 1] != INVALID) uf_union(P, i, i + WW + 1);
    }
}

__global__ void k_count(const uint32_t* __restrict__ P, uint32_t* c) {
    uint32_t roots = 0;
    int stride = gridDim.x * blockDim.x;
    for (int i = blockIdx.x * blockDim.x + threadIdx.x; i < NPIX; i += stride) {
        uint32_t p = P[i];
        if (p == (uint32_t)i && p != INVALID) {
            if (i > 0) roots++;
            else atomicOr(&c[4], 1u);  // singleton fg component at pixel 0 -> label 0
        }
    }
    for (int off = 32; off > 0; off >>= 1) roots += __shfl_down(roots, off);
    __shared__ uint32_t s[4];
    if ((threadIdx.x & 63) == 0) s[threadIdx.x >> 6] = roots;
    __syncthreads();
    if (threadIdx.x == 0) {
        uint32_t t = s[0] + s[1] + s[2] + s[3];
        if (t) atomicAdd(&c[3], t);
    }
}

__global__ void k_fin_input(uint32_t* c, int is_lab) {
    uint32_t numFg = c[2];
    uint32_t uniq = c[3] + ((numFg < (uint32_t)NPIX || c[4]) ? 1u : 0u);
    if (is_lab) {
        c[9] = uniq;
        c[10] = __float_as_uint((float)numFg);  // exact integer < 2^24
    } else {
        c[8] = uniq;
    }
}

__global__ void k_final(const uint32_t* __restrict__ c, float* __restrict__ out) {
    float ccs = (float)c[8];
    float ccsg = (float)c[9];
    float numSg = __uint_as_float(c[10]);
    out[0] = fabsf(ccsg - ccs) / numSg;
}

extern "C" void kernel_launch(void* const* d_in, const int* in_sizes, int n_in,
                              void* d_out, int out_size, void* d_ws, size_t ws_size,
                              hipStream_t stream) {
    const float* img = (const float*)d_in[0];
    const float* lab = (const float*)d_in[1];
    float* out = (float*)d_out;
    char* ws = (char*)d_ws;

    float* bufA = (float*)ws;                                   // 16 MB (P)
    float* bufB = (float*)(ws + (size_t)NPIX * sizeof(float));  // 16 MB (opened)
    uint32_t* cnt = (uint32_t*)(ws + (size_t)2 * NPIX * sizeof(float));
    uint32_t* P = (uint32_t*)bufA;

    const int gridPix = NPIX / 256;  // 16384

    for (int t = 0; t < 2; ++t) {
        const float* src = (t == 0) ? img : lab;
        k_zero<<<1, 1, 0, stream>>>(cnt, t == 0 ? 1 : 0);
        k_open<<<NTILES, 256, 0, stream>>>(src, bufB, cnt);
        k_ccl<<<NTILES, 256, 0, stream>>>(bufB, cnt, P);
        k_border<<<gridPix, 256, 0, stream>>>(P);
        k_count<<<gridPix / 4, 256, 0, stream>>>(P, cnt);
        k_fin_input<<<1, 1, 0, stream>>>(cnt, t);
    }
    k_final<<<1, 1, 0, stream>>>(cnt, out);
}

// Round 3
// 315.330 us; speedup vs baseline: 2.2417x; 1.7729x over previous
//
#include <hip/hip_runtime.h>
#include <stdint.h>

#define WW 1024
#define HH 1024
#define NB 4
#define HW (HH * WW)
#define NPIX (NB * HW)        // 4194304
#define NTILES (NB * 32 * 32) // 4096 tiles of 32x32
#define INVALID 0xFFFFFFFFu
#define RS 8                  // rows per k_open block

// counters (uint32 words):
// scratch: [0]=min_bits [1]=max_bits [2]=numFg [3]=roots(>0) [4]=root0_flag
// persist: [8]=ccs_uniq [9]=ccsg_uniq [10]=numSg_float_bits

__global__ void k_zero(uint32_t* c, int first) {
    c[0] = 0x7F800000u;  // +inf (data >= 0 so uint-bit order == float order)
    c[1] = 0u;
    c[2] = 0u; c[3] = 0u; c[4] = 0u;
    if (first) { c[8] = 0u; c[9] = 0u; c[10] = 0u; }
}

// ---- fused opening (cross erode+dilate) + global min/max, row-sweep --------
// block = full-width strip of RS rows; thread t owns cols 4t..4t+3 (float4).
// er(y) = min(hmin3(in y), in y-1, in y+1); dil(y) = max(hmax3(er y), er y±1)
__global__ void k_open(const float* __restrict__ in, float* __restrict__ out,
                       uint32_t* c) {
    int b  = blockIdx.x >> 7;            // 128 strips per image
    int y0 = (blockIdx.x & 127) * RS;
    int t  = threadIdx.x;
    const float4* inb = (const float4*)(in + (size_t)b * HW);
    float4* outb      = (float4*)(out + (size_t)b * HW);

    // load all RS+4 input rows up-front (independent, all in flight)
    float4 A[RS + 4];
    #pragma unroll
    for (int j = 0; j < RS + 4; j++) {
        int iy = y0 - 2 + j;
        if (iy >= 0 && iy < HH) A[j] = inb[iy * 256 + t];
        else A[j] = make_float4(1e10f, 1e10f, 1e10f, 1e10f);  // erosion pad
    }

    __shared__ float sx[RS + 2][258];
    __shared__ float sw[RS + 2][258];
    #pragma unroll
    for (int r = 0; r < RS + 2; r++) { sx[r][t + 1] = A[r + 1].x; sw[r][t + 1] = A[r + 1].w; }
    if (t < RS + 2) { sw[t][0] = 1e10f; sx[t][257] = 1e10f; }
    __syncthreads();

    float4 E[RS + 2];  // er rows y0-1 .. y0+RS
    #pragma unroll
    for (int r = 0; r < RS + 2; r++) {
        int ey = y0 - 1 + r;
        float lw = sw[r][t], rw = sx[r][t + 2];
        float4 v = A[r + 1];
        float hx = fminf(fminf(lw, v.x), v.y);
        float hy = fminf(fminf(v.x, v.y), v.z);
        float hz = fminf(fminf(v.y, v.z), v.w);
        float hw = fminf(fminf(v.z, v.w), rw);
        float4 e;
        e.x = fminf(hx, fminf(A[r].x, A[r + 2].x));
        e.y = fminf(hy, fminf(A[r].y, A[r + 2].y));
        e.z = fminf(hz, fminf(A[r].z, A[r + 2].z));
        e.w = fminf(hw, fminf(A[r].w, A[r + 2].w));
        if (ey < 0 || ey >= HH) e = make_float4(-1e10f, -1e10f, -1e10f, -1e10f); // dilation pad
        E[r] = e;
    }
    __syncthreads();  // phase-1 reads done; reuse LDS

    #pragma unroll
    for (int d = 0; d < RS; d++) { sx[d][t + 1] = E[d + 1].x; sw[d][t + 1] = E[d + 1].w; }
    if (t < RS) { sw[t][0] = -1e10f; sx[t][257] = -1e10f; }
    __syncthreads();

    float lmin = __uint_as_float(0x7F800000u);
    float lmax = 0.0f;
    #pragma unroll
    for (int d = 0; d < RS; d++) {
        float lw = sw[d][t], rw = sx[d][t + 2];
        float4 v = E[d + 1];
        float hx = fmaxf(fmaxf(lw, v.x), v.y);
        float hy = fmaxf(fmaxf(v.x, v.y), v.z);
        float hz = fmaxf(fmaxf(v.y, v.z), v.w);
        float hw = fmaxf(fmaxf(v.z, v.w), rw);
        float4 o;
        o.x = fmaxf(hx, fmaxf(E[d].x, E[d + 2].x));
        o.y = fmaxf(hy, fmaxf(E[d].y, E[d + 2].y));
        o.z = fmaxf(hz, fmaxf(E[d].z, E[d + 2].z));
        o.w = fmaxf(hw, fmaxf(E[d].w, E[d + 2].w));
        outb[(y0 + d) * 256 + t] = o;
        lmin = fminf(lmin, fminf(fminf(o.x, o.y), fminf(o.z, o.w)));
        lmax = fmaxf(lmax, fmaxf(fmaxf(o.x, o.y), fmaxf(o.z, o.w)));
    }
    for (int off = 32; off > 0; off >>= 1) {
        lmin = fminf(lmin, __shfl_down(lmin, off));
        lmax = fmaxf(lmax, __shfl_down(lmax, off));
    }
    __shared__ float smin[4], smax[4];
    if ((t & 63) == 0) { smin[t >> 6] = lmin; smax[t >> 6] = lmax; }
    __syncthreads();
    if (t == 0) {
        float m0 = fminf(fminf(smin[0], smin[1]), fminf(smin[2], smin[3]));
        float m1 = fmaxf(fmaxf(smax[0], smax[1]), fmaxf(smax[2], smax[3]));
        atomicMin(&c[0], __float_as_uint(m0));  // non-negative floats
        atomicMax(&c[1], __float_as_uint(m1));
    }
}

// ---------------- LDS union-find helpers (workgroup scope) ------------------
__device__ __forceinline__ uint32_t lload(uint32_t* lp, uint32_t x) {
    return __hip_atomic_load(&lp[x], __ATOMIC_RELAXED, __HIP_MEMORY_SCOPE_WORKGROUP);
}
__device__ __forceinline__ uint32_t lfind(uint32_t* lp, uint32_t x) {
    uint32_t p = lload(lp, x);
    while (p != x) {
        uint32_t gp = lload(lp, p);
        if (gp != p)
            __hip_atomic_store(&lp[x], gp, __ATOMIC_RELAXED, __HIP_MEMORY_SCOPE_WORKGROUP);
        x = p; p = gp;
    }
    return x;
}
__device__ void lunion(uint32_t* lp, uint32_t a, uint32_t b) {
    uint32_t ra = lfind(lp, a), rb = lfind(lp, b);
    while (ra != rb) {
        uint32_t hi = ra > rb ? ra : rb;
        uint32_t lo = ra ^ rb ^ hi;
        uint32_t old = atomicCAS(&lp[lo], lo, hi);
        if (old == lo) return;
        ra = lfind(lp, old);
        rb = lfind(lp, hi);
    }
}

// ---------------- binarize + tile-local CCL ---------------------------------
__global__ void k_ccl(const float* __restrict__ opened, uint32_t* c,
                      uint32_t* __restrict__ P) {
    int tile = blockIdx.x;
    int b  = tile >> 10;
    int tt = tile & 1023;
    int ty0 = (tt >> 5) << 5;
    int tx0 = (tt & 31) << 5;
    uint32_t base = (uint32_t)b * HW + (uint32_t)ty0 * WW + tx0;

    float mn = __uint_as_float(c[0]);
    float mx = __uint_as_float(c[1]);
    float denom = (mx - mn) + 1e-10f;  // reference association order

    __shared__ uint32_t lp[1024];
    int trow = threadIdx.x >> 3;        // 0..31
    int tc4  = (threadIdx.x & 7) << 2;  // 0,4,..,28
    const float4* op4 = (const float4*)(opened + base);
    float4 v = op4[trow * 256 + (tc4 >> 2)];
    int li0 = (trow << 5) + tc4;
    uint32_t m0 = ((v.x - mn) / denom >= 0.5f) ? 1u : 0u;  // IEEE f32 div
    uint32_t m1 = ((v.y - mn) / denom >= 0.5f) ? 1u : 0u;
    uint32_t m2 = ((v.z - mn) / denom >= 0.5f) ? 1u : 0u;
    uint32_t m3 = ((v.w - mn) / denom >= 0.5f) ? 1u : 0u;
    lp[li0 + 0] = m0 ? (uint32_t)(li0 + 0) : INVALID;
    lp[li0 + 1] = m1 ? (uint32_t)(li0 + 1) : INVALID;
    lp[li0 + 2] = m2 ? (uint32_t)(li0 + 2) : INVALID;
    lp[li0 + 3] = m3 ? (uint32_t)(li0 + 3) : INVALID;
    uint32_t fgcnt = m0 + m1 + m2 + m3;
    __syncthreads();

    // local unions: W, N, NW, NE (all intra-tile 8-conn edges once)
    #pragma unroll
    for (int q = 0; q < 4; q++) {
        int li = q * 256 + threadIdx.x;
        if (lload(lp, li) == INVALID) continue;
        int ly = li >> 5, lx = li & 31;
        if (lx > 0 && lload(lp, li - 1) != INVALID) lunion(lp, li, li - 1);
        if (ly > 0) {
            if (lload(lp, li - 32) != INVALID)            lunion(lp, li, li - 32);
            if (lx > 0 && lload(lp, li - 33) != INVALID)  lunion(lp, li, li - 33);
            if (lx < 31 && lload(lp, li - 31) != INVALID) lunion(lp, li, li - 31);
        }
    }
    __syncthreads();

    // flatten + write global parents (depth-1 trees to tile-local max)
    uint4 g;
    uint32_t* gp = &g.x;
    #pragma unroll
    for (int j = 0; j < 4; j++) {
        int li = li0 + j;
        if (lp[li] == INVALID) gp[j] = INVALID;
        else {
            uint32_t r = lfind(lp, li);
            gp[j] = base + (uint32_t)(r >> 5) * WW + (r & 31);
        }
    }
    *(uint4*)(P + base + (uint32_t)trow * WW + tc4) = g;

    for (int off = 32; off > 0; off >>= 1) fgcnt += __shfl_down(fgcnt, off);
    __shared__ uint32_t s[4];
    if ((threadIdx.x & 63) == 0) s[threadIdx.x >> 6] = fgcnt;
    __syncthreads();
    if (threadIdx.x == 0) {
        uint32_t sum = s[0] + s[1] + s[2] + s[3];
        if (sum) atomicAdd(&c[2], sum);
    }
}

// ---------------- global union-find (device scope, cross-XCD safe) ----------
__device__ __forceinline__ uint32_t pload(uint32_t* P, uint32_t x) {
    return __hip_atomic_load(&P[x], __ATOMIC_RELAXED, __HIP_MEMORY_SCOPE_AGENT);
}
__device__ __forceinline__ uint32_t uf_find(uint32_t* P, uint32_t x) {
    uint32_t p = pload(P, x);
    while (p != x) {
        uint32_t gp = pload(P, p);
        if (gp != p)
            __hip_atomic_store(&P[x], gp, __ATOMIC_RELAXED, __HIP_MEMORY_SCOPE_AGENT);
        x = p; p = gp;
    }
    return x;
}
__device__ void uf_union(uint32_t* P, uint32_t a, uint32_t b) {
    uint32_t ra = uf_find(P, a);
    uint32_t rb = uf_find(P, b);
    while (ra != rb) {
        uint32_t hi = ra > rb ? ra : rb;
        uint32_t lo = ra ^ rb ^ hi;
        uint32_t old = atomicCAS(&P[lo], lo, hi);
        if (old == lo) return;
        ra = uf_find(P, old);
        rb = uf_find(P, hi);
    }
}

// border pixels only: 96 candidates per tile (lx==0 col, lx==31 col, ly==31 row)
__global__ void k_border(uint32_t* P) {
    int tid = blockIdx.x * 256 + threadIdx.x;
    int tile = tid / 96;
    int k = tid - tile * 96;
    int b  = tile >> 10;
    int tt = tile & 1023;
    int ty0 = (tt >> 5) << 5;
    int tx0 = (tt & 31) << 5;
    int g = k >> 5, o = k & 31;
    int ly, lx;
    if (g == 0)      { ly = o;  lx = 0; }
    else if (g == 1) { ly = o;  lx = 31; }
    else             { ly = 31; lx = o; }   // corners duplicated: harmless
    int x = tx0 + lx, y = ty0 + ly;
    int i = b * HW + y * WW + x;
    if (P[i] == INVALID) return;
    bool xe = (x < WW - 1), ys = (y < HH - 1);
    if (lx == 31 && xe && P[i + 1] != INVALID) uf_union(P, i, i + 1);
    if (ys) {
        bool cS = (ly == 31);
        if (cS && P[i + WW] != INVALID)                            uf_union(P, i, i + WW);
        if ((cS || lx == 0)  && x > 0 && P[i + WW - 1] != INVALID) uf_union(P, i, i + WW - 1);
        if ((cS || lx == 31) && xe    && P[i + WW + 1] != INVALID) uf_union(P, i, i + WW + 1);
    }
}

__global__ void k_count(const uint32_t* __restrict__ P, uint32_t* c) {
    const uint4* P4 = (const uint4*)P;
    uint32_t roots = 0;
    int stride = gridDim.x * blockDim.x;
    for (int idx = blockIdx.x * blockDim.x + threadIdx.x; idx < NPIX / 4; idx += stride) {
        uint4 p = P4[idx];
        uint32_t base = (uint32_t)idx * 4;
        if (p.x == base) { if (base > 0) roots++; else atomicOr(&c[4], 1u); }
        if (p.y == base + 1) roots++;
        if (p.z == base + 2) roots++;
        if (p.w == base + 3) roots++;
    }
    for (int off = 32; off > 0; off >>= 1) roots += __shfl_down(roots, off);
    __shared__ uint32_t s[4];
    if ((threadIdx.x & 63) == 0) s[threadIdx.x >> 6] = roots;
    __syncthreads();
    if (threadIdx.x == 0) {
        uint32_t t = s[0] + s[1] + s[2] + s[3];
        if (t) atomicAdd(&c[3], t);
    }
}

__global__ void k_fin_input(uint32_t* c, int is_lab) {
    uint32_t numFg = c[2];
    uint32_t uniq = c[3] + ((numFg < (uint32_t)NPIX || c[4]) ? 1u : 0u);
    if (is_lab) {
        c[9] = uniq;
        c[10] = __float_as_uint((float)numFg);  // exact integer < 2^24
    } else {
        c[8] = uniq;
    }
}

__global__ void k_final(const uint32_t* __restrict__ c, float* __restrict__ out) {
    float ccs = (float)c[8];
    float ccsg = (float)c[9];
    float numSg = __uint_as_float(c[10]);
    out[0] = fabsf(ccsg - ccs) / numSg;
}

extern "C" void kernel_launch(void* const* d_in, const int* in_sizes, int n_in,
                              void* d_out, int out_size, void* d_ws, size_t ws_size,
                              hipStream_t stream) {
    const float* img = (const float*)d_in[0];
    const float* lab = (const float*)d_in[1];
    float* out = (float*)d_out;
    char* ws = (char*)d_ws;

    float* bufA = (float*)ws;                                   // 16 MB (P)
    float* bufB = (float*)(ws + (size_t)NPIX * sizeof(float));  // 16 MB (opened)
    uint32_t* cnt = (uint32_t*)(ws + (size_t)2 * NPIX * sizeof(float));
    uint32_t* P = (uint32_t*)bufA;

    for (int t = 0; t < 2; ++t) {
        const float* src = (t == 0) ? img : lab;
        k_zero<<<1, 1, 0, stream>>>(cnt, t == 0 ? 1 : 0);
        k_open<<<NB * (HH / RS), 256, 0, stream>>>(src, bufB, cnt);
        k_ccl<<<NTILES, 256, 0, stream>>>(bufB, cnt, P);
        k_border<<<(NTILES * 96) / 256, 256, 0, stream>>>(P);
        k_count<<<2048, 256, 0, stream>>>(P, cnt);
        k_fin_input<<<1, 1, 0, stream>>>(cnt, t);
    }
    k_final<<<1, 1, 0, stream>>>(cnt, out);
}